// Round 14
// baseline (41.800 us; speedup 1.0000x reference)
//
#include <hip/hip_runtime.h>
#include <math.h>

#define SF 0.99999f
#define PI2 6.283185307179586476925f
#define SWZ(c) ((c) ^ (((c) >> 4) & 15))
// compiler-only fence: orders same-wave LDS write/read phases.
#define LDSFENCE() asm volatile("" ::: "memory")

template<int SGN>
__device__ __forceinline__ void twmul(float& ur, float& ui, float c, float s) {
    const float ss = (SGN < 0) ? -s : s;
    const float r = ur * c - ui * ss;
    const float i = ui * c + ur * ss;
    ur = r; ui = i;
}

// 8-point DFT across registers. SGN=-1: forward; SGN=+1: inverse.
template<int SGN>
__device__ __forceinline__ void bfly8(float* ur, float* ui) {
    const float C2 = 0.70710678118654752440f;
    float ar[4], ai[4], br[4], bi[4];
#pragma unroll
    for (int m = 0; m < 4; ++m) {
        ar[m] = ur[m] + ur[m + 4]; ai[m] = ui[m] + ui[m + 4];
        br[m] = ur[m] - ur[m + 4]; bi[m] = ui[m] - ui[m + 4];
    }
    float b1r, b1i, b2r, b2i, b3r, b3i;
    if (SGN < 0) {
        b1r = C2 * (br[1] + bi[1]); b1i = C2 * (bi[1] - br[1]);
        b2r = bi[2];                b2i = -br[2];
        b3r = C2 * (bi[3] - br[3]); b3i = -C2 * (br[3] + bi[3]);
    } else {
        b1r = C2 * (br[1] - bi[1]); b1i = C2 * (bi[1] + br[1]);
        b2r = -bi[2];               b2i = br[2];
        b3r = -C2 * (br[3] + bi[3]); b3i = C2 * (br[3] - bi[3]);
    }
    const float e0r = ar[0] + ar[2], e0i = ai[0] + ai[2];
    const float e1r = ar[0] - ar[2], e1i = ai[0] - ai[2];
    const float o0r = ar[1] + ar[3], o0i = ai[1] + ai[3];
    const float o1r = ar[1] - ar[3], o1i = ai[1] - ai[3];
    ur[0] = e0r + o0r; ui[0] = e0i + o0i;
    ur[4] = e0r - o0r; ui[4] = e0i - o0i;
    if (SGN < 0) { ur[2] = e1r + o1i; ui[2] = e1i - o1r; ur[6] = e1r - o1i; ui[6] = e1i + o1r; }
    else         { ur[2] = e1r - o1i; ui[2] = e1i + o1r; ur[6] = e1r + o1i; ui[6] = e1i - o1r; }
    const float f0r = br[0] + b2r, f0i = bi[0] + b2i;
    const float f1r = br[0] - b2r, f1i = bi[0] - b2i;
    const float g0r = b1r + b3r, g0i = b1i + b3i;
    const float g1r = b1r - b3r, g1i = b1i - b3i;
    ur[1] = f0r + g0r; ui[1] = f0i + g0i;
    ur[5] = f0r - g0r; ui[5] = f0i - g0i;
    if (SGN < 0) { ur[3] = f1r + g1i; ui[3] = f1i - g1r; ur[7] = f1r - g1i; ui[7] = f1i + g1r; }
    else         { ur[3] = f1r - g1i; ui[3] = f1i + g1r; ur[7] = f1r + g1i; ui[7] = f1i - g1r; }
}

// Wave-local 512-pt complex FFT, Stockham radix-8, 3 stages, single LDS buffer.
// ra[8] = hoisted read indices SWZ(t+64m). Writes per-element inline SWZ.
// No barriers (each wave uses its own buffer; LDS ops retire in order per wave).
template<int SGN>
__device__ __forceinline__ void fft512w(float* ur, float* ui,
                                        float2* __restrict__ buf,
                                        const float2* __restrict__ tw2,
                                        const float2* __restrict__ tw3,
                                        const int* ra, int t) {
    bfly8<SGN>(ur, ui);
    LDSFENCE();
#pragma unroll
    for (int m = 0; m < 8; ++m) buf[SWZ(8 * t + m)] = make_float2(ur[m], ui[m]);
    LDSFENCE();
#pragma unroll
    for (int m = 0; m < 8; ++m) { const float2 v = buf[ra[m]]; ur[m] = v.x; ui[m] = v.y; }
    const int k2 = t & 7;
#pragma unroll
    for (int m = 1; m < 8; ++m) { const float2 w = tw2[m * 8 + k2]; twmul<SGN>(ur[m], ui[m], w.x, w.y); }
    bfly8<SGN>(ur, ui);
    const int jj = ((t >> 3) << 6) + k2;
    LDSFENCE();
#pragma unroll
    for (int m = 0; m < 8; ++m) buf[SWZ(jj + 8 * m)] = make_float2(ur[m], ui[m]);
    LDSFENCE();
#pragma unroll
    for (int m = 0; m < 8; ++m) { const float2 v = buf[ra[m]]; ur[m] = v.x; ui[m] = v.y; }
#pragma unroll
    for (int m = 1; m < 8; ++m) { const float2 w = tw3[m * 64 + t]; twmul<SGN>(ur[m], ui[m], w.x, w.y); }
    bfly8<SGN>(ur, ui);
    LDSFENCE();
}

// TWO waves cooperate on ONE element: wave w owns frame/partition pair (2w,2w+1).
// Critical path: 6 FFT-times (vs 9 single-wave). 5 block barriers.
__global__ __launch_bounds__(128, 2) void pbfd_kernel(
    const float* __restrict__ g_mic,   // (B,256)
    const float* __restrict__ g_lsb,   // (B,1280)
    const float* __restrict__ g_phie,  // (B,257)
    const float* __restrict__ g_p1,    // (B,257,4)
    const float* __restrict__ g_hr,    // (B,257,4)
    const float* __restrict__ g_hi,    // (B,257,4)
    float* __restrict__ g_out)         // (B,256)
{
    __shared__ float2 tw2[64];
    __shared__ float2 tw3[512];
    __shared__ float2 xch[2][512];     // one exchange buffer per wave; also used for partial shares

    const int tid = threadIdx.x;       // 0..127
    const int w = tid >> 6;            // wave id 0/1
    const int t = tid & 63;
    const int elem = blockIdx.x;       // grid == B
    float2* buf  = &xch[w][0];
    float2* bufo = &xch[1 ^ w][0];
    const int ml = (64 - t) & 63;      // mirror lane

    // ---- twiddle tables (block-shared) ----
    for (int e = tid; e < 512; e += 128) {
        const int m = e >> 6, tt = e & 63;
        float s, c;
        sincosf(PI2 * (float)(m * tt) * (1.0f / 512.0f), &s, &c);
        tw3[e] = make_float2(c, s);
    }
    if (tid < 64) {
        const int m = tid >> 3, k = tid & 7;
        float s, c;
        sincosf(PI2 * (float)(m * k) * (1.0f / 64.0f), &s, &c);
        tw2[tid] = make_float2(c, s);
    }
    __syncthreads();  // (1) tables ready

    // ---- hoisted LDS read indices ----
    int ra[8];
#pragma unroll
    for (int m = 0; m < 8; ++m) ra[m] = SWZ(t + 64 * m);

    float mv[4];
    {
        const float* mp = g_mic + (size_t)elem * 256;
#pragma unroll
        for (int q = 0; q < 4; ++q) mv[q] = mp[t + 64 * q];
    }

    // ---- X: this wave's frame pair (2w, 2w+1) as ONE packed complex FFT ----
    float xrl[2][4], xil[2][4], xnl[2];
    {
        const float* lb = g_lsb + (size_t)elem * 1280;
        float ur[8], ui[8];
#pragma unroll
        for (int m = 0; m < 8; ++m) {
            ur[m] = lb[(2 * w) * 256 + t + 64 * m];
            ui[m] = lb[(2 * w + 1) * 256 + t + 64 * m];
        }
        fft512w<-1>(ur, ui, buf, tw2, tw3, ra, t);
#pragma unroll
        for (int m = 0; m < 4; ++m) {
            float zmr = __shfl(ur[7 - m], ml);
            float zmi = __shfl(ui[7 - m], ml);
            if (t == 0) {  // lane0: mirror of bin 64m is slot 8-m (self for m=0)
                zmr = (m == 0) ? ur[0] : ur[8 - m];
                zmi = (m == 0) ? ui[0] : ui[8 - m];
            }
            xrl[0][m] = 0.5f * (ur[m] + zmr);
            xil[0][m] = 0.5f * (ui[m] - zmi);
            xrl[1][m] = 0.5f * (ui[m] + zmi);
            xil[1][m] = -0.5f * (ur[m] - zmr);
        }
        if (t == 0) { xnl[0] = ur[4]; xnl[1] = ui[4]; }  // X[256] re/im-packed
    }

    // Hermitian IFFT helper (own buffer): o4[q] = Re(ifft)[256+t+64q]/512.
    auto herm_ifft = [&](const float cr[4], const float ci[4], float cn, float o4[4]) {
        float ur[8], ui[8];
#pragma unroll
        for (int m = 0; m < 4; ++m) { ur[m] = cr[m]; ui[m] = ci[m]; }
#pragma unroll
        for (int m = 4; m < 8; ++m) {
            ur[m] = __shfl(cr[7 - m], ml);
            ui[m] = -__shfl(ci[7 - m], ml);
        }
        if (t == 0) {
            ur[5] = cr[3]; ui[5] = -ci[3];
            ur[6] = cr[2]; ui[6] = -ci[2];
            ur[7] = cr[1]; ui[7] = -ci[1];
            ur[4] = cn; ui[4] = 0.f;  // Nyquist: real
        }
        fft512w<1>(ur, ui, buf, tw2, tw3, ra, t);
#pragma unroll
        for (int q = 0; q < 4; ++q) o4[q] = ur[4 + q] * (1.0f / 512.0f);
    };

    // ---- partial C_w = sum_{j in pair} X_j*H_j ; share; full C; redundant est-IFFT ----
    float d4[4];
    float pnl[2] = {0, 0}, en = 0.f, pen = 0.f;  // lane0 side channel (pair-local P1 nyq)
    {
        float cr[4], ci[4], cn = 0.f;
        {
            const float2* hr2 = (const float2*)(g_hr + (size_t)elem * 1028);  // [bin*2 + w]
            const float2* hi2 = (const float2*)(g_hi + (size_t)elem * 1028);
#pragma unroll
            for (int m = 0; m < 4; ++m) {
                const int bin = t + 64 * m;
                const float2 a = hr2[bin * 2 + w];
                const float2 b = hi2[bin * 2 + w];
                cr[m] = xrl[0][m] * a.x - xil[0][m] * b.x + xrl[1][m] * a.y - xil[1][m] * b.y;
                ci[m] = xrl[0][m] * b.x + xil[0][m] * a.x + xrl[1][m] * b.y + xil[1][m] * a.y;
            }
            if (t == 0) {
                const float2 a = hr2[256 * 2 + w];
                const float2 p = ((const float2*)(g_p1 + (size_t)elem * 1028))[256 * 2 + w];
                cn = xnl[0] * a.x + xnl[1] * a.y;
                pnl[0] = p.x; pnl[1] = p.y;
            }
        }
        // share partial C through own exchange buffer (plain indices, conflict-free)
#pragma unroll
        for (int m = 0; m < 4; ++m) buf[t + 64 * m] = make_float2(cr[m], ci[m]);
        if (t == 0) buf[256] = make_float2(cn, 0.f);
        __syncthreads();  // (2) partials written
#pragma unroll
        for (int m = 0; m < 4; ++m) {
            const float2 v = bufo[t + 64 * m];
            cr[m] += v.x; ci[m] += v.y;
        }
        if (t == 0) cn += bufo[256].x;
        __syncthreads();  // (3) partials consumed; buffers free for FFT reuse
        float o4[4];
        herm_ifft(cr, ci, cn, o4);  // redundant in both waves (identical data)
#pragma unroll
        for (int q = 0; q < 4; ++q) d4[q] = mv[q] - o4[q];
    }

    // ---- E = FFT([zeros(256); d]) (redundant, identical in both waves) ----
    float er[4], ei[4];
    {
        float ur[8], ui[8];
#pragma unroll
        for (int m = 0; m < 4; ++m) { ur[m] = 0.f; ui[m] = 0.f; }
#pragma unroll
        for (int q = 0; q < 4; ++q) { ur[4 + q] = d4[q]; ui[4 + q] = 0.f; }
        fft512w<-1>(ur, ui, buf, tw2, tw3, ra, t);
#pragma unroll
        for (int m = 0; m < 4; ++m) { er[m] = ur[m]; ei[m] = ui[m]; }
        if (t == 0) en = ur[4];
    }

    // ---- phi_e (redundant) ----
    float pe[4];
    {
        const float* php = g_phie + (size_t)elem * 257;
#pragma unroll
        for (int m = 0; m < 4; ++m)
            pe[m] = 0.7f * php[t + 64 * m] + 0.3f * (er[m] * er[m] + ei[m] * ei[m]);
        if (t == 0) pen = 0.7f * php[256] + 0.3f * en * en;
    }

    // ---- gradient: THIS wave's pair only: IFFT(KE0+i*KE1) -> mask -> FFT ->
    //      unpack fd_dH, partial D_w = sum_{j in pair} X_j * fd_j ----
    float Dr[4], Di[4];
    float dn = 0.f;
    {
        const float2* p12 = (const float2*)(g_p1 + (size_t)elem * 1028);  // [bin*2 + w]
        float ur[8], ui[8], gr[4], gi[4];
#pragma unroll
        for (int m = 0; m < 4; ++m) {
            const float2 p = p12[(t + 64 * m) * 2 + w];
            const float pa = p.x, pb = p.y;
            const float xxa = xrl[0][m] * xrl[0][m] + xil[0][m] * xil[0][m];
            const float Ra = xxa * pa + 2.f * pe[m] + 1e-10f;
            const float ia = 1.f / Ra;
            const float kra = pa * xrl[0][m] * ia, kia = -pa * xil[0][m] * ia;
            const float a_r = kra * er[m] - kia * ei[m];
            const float a_i = kra * ei[m] + kia * er[m];
            const float xxb = xrl[1][m] * xrl[1][m] + xil[1][m] * xil[1][m];
            const float Rb = xxb * pb + 2.f * pe[m] + 1e-10f;
            const float ib = 1.f / Rb;
            const float krb = pb * xrl[1][m] * ib, kib = -pb * xil[1][m] * ib;
            const float b_r = krb * er[m] - kib * ei[m];
            const float b_i = krb * ei[m] + kib * er[m];
            ur[m] = a_r - b_i;  ui[m] = a_i + b_r;   // KE0 + i*KE1 (pair-local)
            gr[m] = a_r + b_i;  gi[m] = b_r - a_i;   // conj-pack for mirror lanes
        }
#pragma unroll
        for (int m = 4; m < 8; ++m) {
            ur[m] = __shfl(gr[7 - m], ml);
            ui[m] = __shfl(gi[7 - m], ml);
        }
        if (t == 0) {
            ur[5] = gr[3]; ui[5] = gi[3];
            ur[6] = gr[2]; ui[6] = gi[2];
            ur[7] = gr[1]; ui[7] = gi[1];
            const float Rn0 = xnl[0] * xnl[0] * pnl[0] + 2.f * pen + 1e-10f;
            const float Rn1 = xnl[1] * xnl[1] * pnl[1] + 2.f * pen + 1e-10f;
            ur[4] = pnl[0] * xnl[0] / Rn0 * en;
            ui[4] = pnl[1] * xnl[1] / Rn1 * en;
        }
        fft512w<1>(ur, ui, buf, tw2, tw3, ra, t);   // -> 512*(dH0 + i*dH1)
#pragma unroll
        for (int m = 0; m < 4; ++m) { ur[m] *= (1.0f / 512.0f); ui[m] *= (1.0f / 512.0f); }
#pragma unroll
        for (int m = 4; m < 8; ++m) { ur[m] = 0.f; ui[m] = 0.f; }
        fft512w<-1>(ur, ui, buf, tw2, tw3, ra, t);  // Z = fd_dH0 + i*fd_dH1
#pragma unroll
        for (int m = 0; m < 4; ++m) {
            float zmr = __shfl(ur[7 - m], ml);
            float zmi = __shfl(ui[7 - m], ml);
            if (t == 0) {
                zmr = (m == 0) ? ur[0] : ur[8 - m];
                zmi = (m == 0) ? ui[0] : ui[8 - m];
            }
            const float f0r = 0.5f * (ur[m] + zmr), f0i = 0.5f * (ui[m] - zmi);
            const float f1r = 0.5f * (ui[m] + zmi), f1i = -0.5f * (ur[m] - zmr);
            Dr[m] = xrl[0][m] * f0r - xil[0][m] * f0i + xrl[1][m] * f1r - xil[1][m] * f1i;
            Di[m] = xrl[0][m] * f0i + xil[0][m] * f0r + xrl[1][m] * f1i + xil[1][m] * f1r;
        }
        if (t == 0) dn = xnl[0] * ur[4] + xnl[1] * ui[4];
    }

    // ---- share partial D; sum; final IFFT (wave0 stores) ----
#pragma unroll
    for (int m = 0; m < 4; ++m) buf[t + 64 * m] = make_float2(Dr[m], Di[m]);
    if (t == 0) buf[256] = make_float2(dn, 0.f);
    __syncthreads();  // (4) D partials written
#pragma unroll
    for (int m = 0; m < 4; ++m) {
        const float2 v = bufo[t + 64 * m];
        Dr[m] += v.x; Di[m] += v.y;
    }
    if (t == 0) dn += bufo[256].x;
    __syncthreads();  // (5) D partials consumed; buffers free

    if (w == 0) {
        float o4[4];
        herm_ifft(Dr, Di, dn, o4);
        float* op = g_out + (size_t)elem * 256;
#pragma unroll
        for (int q = 0; q < 4; ++q)
            op[t + 64 * q] = mv[q] - SF * ((mv[q] - d4[q]) + o4[q]);
    }
}

extern "C" void kernel_launch(void* const* d_in, const int* in_sizes, int n_in,
                              void* d_out, int out_size, void* d_ws, size_t ws_size,
                              hipStream_t stream) {
    const float* mic  = (const float*)d_in[0];
    const float* lsb  = (const float*)d_in[1];
    const float* phie = (const float*)d_in[2];
    // d_in[3] = phi_f: dead for the 'enhanced' output
    const float* p1   = (const float*)d_in[4];
    const float* hr   = (const float*)d_in[5];
    const float* hi   = (const float*)d_in[6];
    float* out = (float*)d_out;

    const int B = in_sizes[0] / 256;  // N_MIC == 1
    pbfd_kernel<<<B, 128, 0, stream>>>(mic, lsb, phie, p1, hr, hi, out);
}

// Round 15
// 38.274 us; speedup vs baseline: 1.0921x; 1.0921x over previous
//
#include <hip/hip_runtime.h>
#include <math.h>

#define SF 0.99999f
#define PI2 6.283185307179586476925f
#define SWZ(c) ((c) ^ (((c) >> 4) & 15))
// compiler-only fence: orders same-wave LDS write/read phases.
#define LDSFENCE() asm volatile("" ::: "memory")

template<int SGN>
__device__ __forceinline__ void twmul(float& ur, float& ui, float c, float s) {
    const float ss = (SGN < 0) ? -s : s;
    const float r = ur * c - ui * ss;
    const float i = ui * c + ur * ss;
    ur = r; ui = i;
}

// 8-point DFT across registers. SGN=-1: forward; SGN=+1: inverse.
template<int SGN>
__device__ __forceinline__ void bfly8(float* ur, float* ui) {
    const float C2 = 0.70710678118654752440f;
    float ar[4], ai[4], br[4], bi[4];
#pragma unroll
    for (int m = 0; m < 4; ++m) {
        ar[m] = ur[m] + ur[m + 4]; ai[m] = ui[m] + ui[m + 4];
        br[m] = ur[m] - ur[m + 4]; bi[m] = ui[m] - ui[m + 4];
    }
    float b1r, b1i, b2r, b2i, b3r, b3i;
    if (SGN < 0) {
        b1r = C2 * (br[1] + bi[1]); b1i = C2 * (bi[1] - br[1]);
        b2r = bi[2];                b2i = -br[2];
        b3r = C2 * (bi[3] - br[3]); b3i = -C2 * (br[3] + bi[3]);
    } else {
        b1r = C2 * (br[1] - bi[1]); b1i = C2 * (bi[1] + br[1]);
        b2r = -bi[2];               b2i = br[2];
        b3r = -C2 * (br[3] + bi[3]); b3i = C2 * (br[3] - bi[3]);
    }
    const float e0r = ar[0] + ar[2], e0i = ai[0] + ai[2];
    const float e1r = ar[0] - ar[2], e1i = ai[0] - ai[2];
    const float o0r = ar[1] + ar[3], o0i = ai[1] + ai[3];
    const float o1r = ar[1] - ar[3], o1i = ai[1] - ai[3];
    ur[0] = e0r + o0r; ui[0] = e0i + o0i;
    ur[4] = e0r - o0r; ui[4] = e0i - o0i;
    if (SGN < 0) { ur[2] = e1r + o1i; ui[2] = e1i - o1r; ur[6] = e1r - o1i; ui[6] = e1i + o1r; }
    else         { ur[2] = e1r - o1i; ui[2] = e1i + o1r; ur[6] = e1r + o1i; ui[6] = e1i - o1r; }
    const float f0r = br[0] + b2r, f0i = bi[0] + b2i;
    const float f1r = br[0] - b2r, f1i = bi[0] - b2i;
    const float g0r = b1r + b3r, g0i = b1i + b3i;
    const float g1r = b1r - b3r, g1i = b1i - b3i;
    ur[1] = f0r + g0r; ui[1] = f0i + g0i;
    ur[5] = f0r - g0r; ui[5] = f0i - g0i;
    if (SGN < 0) { ur[3] = f1r + g1i; ui[3] = f1i - g1r; ur[7] = f1r - g1i; ui[7] = f1i + g1r; }
    else         { ur[3] = f1r - g1i; ui[3] = f1i + g1r; ur[7] = f1r + g1i; ui[7] = f1i - g1r; }
}

// Wave-local 512-pt complex FFT, Stockham radix-8, 3 stages, single LDS buffer.
// ra[8] = hoisted read indices SWZ(t+64m). Writes per-element inline SWZ.
// No barriers (single-wave workgroup; LDS ops retire in order per wave).
template<int SGN>
__device__ __forceinline__ void fft512w(float* ur, float* ui,
                                        float2* __restrict__ buf,
                                        const float2* __restrict__ tw2,
                                        const float2* __restrict__ tw3,
                                        const int* ra, int t) {
    bfly8<SGN>(ur, ui);
    LDSFENCE();
#pragma unroll
    for (int m = 0; m < 8; ++m) buf[SWZ(8 * t + m)] = make_float2(ur[m], ui[m]);
    LDSFENCE();
#pragma unroll
    for (int m = 0; m < 8; ++m) { const float2 v = buf[ra[m]]; ur[m] = v.x; ui[m] = v.y; }
    const int k2 = t & 7;
#pragma unroll
    for (int m = 1; m < 8; ++m) { const float2 w = tw2[m * 8 + k2]; twmul<SGN>(ur[m], ui[m], w.x, w.y); }
    bfly8<SGN>(ur, ui);
    const int jj = ((t >> 3) << 6) + k2;
    LDSFENCE();
#pragma unroll
    for (int m = 0; m < 8; ++m) buf[SWZ(jj + 8 * m)] = make_float2(ur[m], ui[m]);
    LDSFENCE();
#pragma unroll
    for (int m = 0; m < 8; ++m) { const float2 v = buf[ra[m]]; ur[m] = v.x; ui[m] = v.y; }
#pragma unroll
    for (int m = 1; m < 8; ++m) { const float2 w = tw3[m * 64 + t]; twmul<SGN>(ur[m], ui[m], w.x, w.y); }
    bfly8<SGN>(ur, ui);
    LDSFENCE();
}

// ONE WAVE PER BLOCK. Code-size-reduced build: 6 FFT instantiations (was 9).
__global__ __launch_bounds__(64, 2) void pbfd_kernel(
    const float* __restrict__ g_mic,   // (B,256)
    const float* __restrict__ g_lsb,   // (B,1280)
    const float* __restrict__ g_phie,  // (B,257)
    const float* __restrict__ g_p1,    // (B,257,4)
    const float* __restrict__ g_hr,    // (B,257,4)
    const float* __restrict__ g_hi,    // (B,257,4)
    float* __restrict__ g_out)         // (B,256)
{
    __shared__ float2 tw2[64];
    __shared__ float2 tw3[512];
    __shared__ float2 xch[512];

    const int t = threadIdx.x;         // 0..63
    const int elem = blockIdx.x;
    float2* buf = &xch[0];
    const int ml = (64 - t) & 63;  // mirror lane: bin 512-k lives at (ml, 7-m) for t>=1

    // ---- per-block twiddle tables, built by this wave (no barrier needed) ----
    {
        float s3, c3;
        sincosf(PI2 * (float)t * (1.0f / 512.0f), &s3, &c3);
        float cr = 1.f, ci = 0.f;
#pragma unroll
        for (int m = 0; m < 8; ++m) {
            tw3[m * 64 + t] = make_float2(cr, ci);
            const float nr = cr * c3 - ci * s3;
            ci = ci * c3 + cr * s3;
            cr = nr;
        }
        float s2, c2;
        sincosf(PI2 * (float)((t >> 3) * (t & 7)) * (1.0f / 64.0f), &s2, &c2);
        tw2[t] = make_float2(c2, s2);
    }
    LDSFENCE();

    // ---- hoisted LDS read indices ----
    int ra[8];
#pragma unroll
    for (int m = 0; m < 8; ++m) ra[m] = SWZ(t + 64 * m);

    float mv[4];
    {
        const float* mp = g_mic + (size_t)elem * 256;
#pragma unroll
        for (int q = 0; q < 4; ++q) mv[q] = mp[t + 64 * q];
    }

    // ---- X: 4 real frame-FFTs as 2 packed complex FFTs, REAL loop (1 code instance) ----
    float xr0[4], xi0[4], xr1[4], xi1[4], xr2[4], xi2[4], xr3[4], xi3[4];
    float xn0, xn1, xn2, xn3;
    {
        const float* lb = g_lsb + (size_t)elem * 1280;
#pragma unroll 1
        for (int pr = 0; pr < 2; ++pr) {
            float ur[8], ui[8];
            const float* fp = lb + pr * 512;
#pragma unroll
            for (int m = 0; m < 8; ++m) {
                ur[m] = fp[t + 64 * m];
                ui[m] = fp[256 + t + 64 * m];
            }
            fft512w<-1>(ur, ui, buf, tw2, tw3, ra, t);
            float ar[4], ai[4], br_[4], bi_[4];
#pragma unroll
            for (int m = 0; m < 4; ++m) {
                float zmr = __shfl(ur[7 - m], ml);
                float zmi = __shfl(ui[7 - m], ml);
                if (t == 0) {  // lane0: mirror of bin 64m is slot 8-m (self for m=0)
                    zmr = (m == 0) ? ur[0] : ur[8 - m];
                    zmi = (m == 0) ? ui[0] : ui[8 - m];
                }
                ar[m]  = 0.5f * (ur[m] + zmr);
                ai[m]  = 0.5f * (ui[m] - zmi);
                br_[m] = 0.5f * (ui[m] + zmi);
                bi_[m] = -0.5f * (ur[m] - zmr);
            }
            if (pr == 0) {
#pragma unroll
                for (int m = 0; m < 4; ++m) {
                    xr0[m] = ar[m]; xi0[m] = ai[m];
                    xr1[m] = br_[m]; xi1[m] = bi_[m];
                }
                xn0 = ur[4]; xn1 = ui[4];
            } else {
#pragma unroll
                for (int m = 0; m < 4; ++m) {
                    xr2[m] = ar[m]; xi2[m] = ai[m];
                    xr3[m] = br_[m]; xi3[m] = bi_[m];
                }
                xn2 = ur[4]; xn3 = ui[4];
            }
        }
    }

    // Hermitian IFFT of a low-half spectrum: o4[q] = Re(ifft)[256+t+64q]/512.
    auto herm_ifft = [&](const float cr[4], const float ci[4], float cn, float o4[4]) {
        float ur[8], ui[8];
#pragma unroll
        for (int m = 0; m < 4; ++m) { ur[m] = cr[m]; ui[m] = ci[m]; }
#pragma unroll
        for (int m = 4; m < 8; ++m) {  // high slot = conj(mirror-lane low slot 7-m)
            ur[m] = __shfl(cr[7 - m], ml);
            ui[m] = -__shfl(ci[7 - m], ml);
        }
        if (t == 0) {
            ur[5] = cr[3]; ui[5] = -ci[3];
            ur[6] = cr[2]; ui[6] = -ci[2];
            ur[7] = cr[1]; ui[7] = -ci[1];
            ur[4] = cn; ui[4] = 0.f;  // Nyquist: real
        }
        fft512w<1>(ur, ui, buf, tw2, tw3, ra, t);
#pragma unroll
        for (int q = 0; q < 4; ++q) o4[q] = ur[4 + q] * (1.0f / 512.0f);
    };

    // ---- est (H prior): C = sum_j X*H folded into the H loads; d = mic - est ----
    float d4[4];
    float pn[4], en = 0.f, pen = 0.f;  // lane0 side channel
    {
        float cr[4], ci[4], cn = 0.f;
        const float4* hr4 = (const float4*)g_hr + (size_t)elem * 257;
        const float4* hi4 = (const float4*)g_hi + (size_t)elem * 257;
#pragma unroll
        for (int m = 0; m < 4; ++m) {
            const float4 a = hr4[t + 64 * m];
            const float4 b = hi4[t + 64 * m];
            cr[m] = xr0[m] * a.x - xi0[m] * b.x + xr1[m] * a.y - xi1[m] * b.y
                  + xr2[m] * a.z - xi2[m] * b.z + xr3[m] * a.w - xi3[m] * b.w;
            ci[m] = xr0[m] * b.x + xi0[m] * a.x + xr1[m] * b.y + xi1[m] * a.y
                  + xr2[m] * b.z + xi2[m] * a.z + xr3[m] * b.w + xi3[m] * a.w;
        }
        if (t == 0) {
            const float4 a = hr4[256];
            const float4 p = ((const float4*)g_p1)[(size_t)elem * 257 + 256];
            cn = xn0 * a.x + xn1 * a.y + xn2 * a.z + xn3 * a.w;
            pn[0] = p.x; pn[1] = p.y; pn[2] = p.z; pn[3] = p.w;
        }
        float o4[4];
        herm_ifft(cr, ci, cn, o4);
#pragma unroll
        for (int q = 0; q < 4; ++q) d4[q] = mv[q] - o4[q];
    }

    // ---- E = FFT([zeros(256); d]) ----
    float er[4], ei[4];
    {
        float ur[8], ui[8];
#pragma unroll
        for (int m = 0; m < 4; ++m) { ur[m] = 0.f; ui[m] = 0.f; }
#pragma unroll
        for (int q = 0; q < 4; ++q) { ur[4 + q] = d4[q]; ui[4 + q] = 0.f; }
        fft512w<-1>(ur, ui, buf, tw2, tw3, ra, t);
#pragma unroll
        for (int m = 0; m < 4; ++m) { er[m] = ur[m]; ei[m] = ui[m]; }
        if (t == 0) en = ur[4];
    }

    // ---- phi_e ----
    float pe[4];
    {
        const float* php = g_phie + (size_t)elem * 257;
#pragma unroll
        for (int m = 0; m < 4; ++m)
            pe[m] = 0.7f * php[t + 64 * m] + 0.3f * (er[m] * er[m] + ei[m] * ei[m]);
        if (t == 0) pen = 0.7f * php[256] + 0.3f * en * en;
    }

    // ---- gradient: REAL loop over pairs (0,1),(2,3) (2 FFT instances, was 4) ----
    float Dr[4] = {0, 0, 0, 0}, Di[4] = {0, 0, 0, 0};
    float dn = 0.f;  // lane0: D at Nyquist
    {
        const float4* p14 = (const float4*)g_p1 + (size_t)elem * 257;
#pragma unroll 1
        for (int pr = 0; pr < 2; ++pr) {
            // runtime-pr operand selection via explicit register copies (no runtime indexing)
            float xar[4], xai[4], xbr[4], xbi[4];
#pragma unroll
            for (int m = 0; m < 4; ++m) {
                xar[m] = pr ? xr2[m] : xr0[m]; xai[m] = pr ? xi2[m] : xi0[m];
                xbr[m] = pr ? xr3[m] : xr1[m]; xbi[m] = pr ? xi3[m] : xi1[m];
            }
            const float xna = pr ? xn2 : xn0, xnb = pr ? xn3 : xn1;
            const float pna = pr ? pn[2] : pn[0], pnb = pr ? pn[3] : pn[1];

            float ur[8], ui[8], gr[4], gi[4];
#pragma unroll
            for (int m = 0; m < 4; ++m) {
                const float4 p = p14[t + 64 * m];
                const float pa = pr ? p.z : p.x;
                const float pb = pr ? p.w : p.y;
                const float xxa = xar[m] * xar[m] + xai[m] * xai[m];
                const float Ra = xxa * pa + 2.f * pe[m] + 1e-10f;
                const float ia = 1.f / Ra;
                const float kra = pa * xar[m] * ia, kia = -pa * xai[m] * ia;
                const float a_r = kra * er[m] - kia * ei[m];
                const float a_i = kra * ei[m] + kia * er[m];
                const float xxb = xbr[m] * xbr[m] + xbi[m] * xbi[m];
                const float Rb = xxb * pb + 2.f * pe[m] + 1e-10f;
                const float ib = 1.f / Rb;
                const float krb = pb * xbr[m] * ib, kib = -pb * xbi[m] * ib;
                const float b_r = krb * er[m] - kib * ei[m];
                const float b_i = krb * ei[m] + kib * er[m];
                ur[m] = a_r - b_i;  ui[m] = a_i + b_r;   // KE_a + i*KE_b
                gr[m] = a_r + b_i;  gi[m] = b_r - a_i;   // conj-pack for mirror lanes
            }
#pragma unroll
            for (int m = 4; m < 8; ++m) {
                ur[m] = __shfl(gr[7 - m], ml);
                ui[m] = __shfl(gi[7 - m], ml);
            }
            if (t == 0) {
                ur[5] = gr[3]; ui[5] = gi[3];
                ur[6] = gr[2]; ui[6] = gi[2];
                ur[7] = gr[1]; ui[7] = gi[1];
                const float Rn0 = xna * xna * pna + 2.f * pen + 1e-10f;
                const float Rn1 = xnb * xnb * pnb + 2.f * pen + 1e-10f;
                ur[4] = pna * xna / Rn0 * en;   // KE_a[256] (real)
                ui[4] = pnb * xnb / Rn1 * en;   // KE_b[256] (real)
            }
            fft512w<1>(ur, ui, buf, tw2, tw3, ra, t);  // -> 512*(dH_a + i*dH_b)
            // mask n<256 (slots m<4), scale 1/512, FFT the still-packed pair
#pragma unroll
            for (int m = 0; m < 4; ++m) { ur[m] *= (1.0f / 512.0f); ui[m] *= (1.0f / 512.0f); }
#pragma unroll
            for (int m = 4; m < 8; ++m) { ur[m] = 0.f; ui[m] = 0.f; }
            fft512w<-1>(ur, ui, buf, tw2, tw3, ra, t);  // Z = fd_a + i*fd_b
            // unpack at low slots; accumulate D += X_a*fd_a + X_b*fd_b
#pragma unroll
            for (int m = 0; m < 4; ++m) {
                float zmr = __shfl(ur[7 - m], ml);
                float zmi = __shfl(ui[7 - m], ml);
                if (t == 0) {
                    zmr = (m == 0) ? ur[0] : ur[8 - m];
                    zmi = (m == 0) ? ui[0] : ui[8 - m];
                }
                const float f0r = 0.5f * (ur[m] + zmr), f0i = 0.5f * (ui[m] - zmi);
                const float f1r = 0.5f * (ui[m] + zmi), f1i = -0.5f * (ur[m] - zmr);
                Dr[m] += xar[m] * f0r - xai[m] * f0i + xbr[m] * f1r - xbi[m] * f1i;
                Di[m] += xar[m] * f0i + xai[m] * f0r + xbr[m] * f1i + xbi[m] * f1r;
            }
            if (t == 0) dn += xna * ur[4] + xnb * ui[4];
        }
    }

    // ---- enhanced = mic - SF*(est + irfft(D)[256:]) ;  est = mic - d ----
    {
        float o4[4];
        herm_ifft(Dr, Di, dn, o4);
        float* op = g_out + (size_t)elem * 256;
#pragma unroll
        for (int q = 0; q < 4; ++q)
            op[t + 64 * q] = mv[q] - SF * ((mv[q] - d4[q]) + o4[q]);
    }
}

extern "C" void kernel_launch(void* const* d_in, const int* in_sizes, int n_in,
                              void* d_out, int out_size, void* d_ws, size_t ws_size,
                              hipStream_t stream) {
    const float* mic  = (const float*)d_in[0];
    const float* lsb  = (const float*)d_in[1];
    const float* phie = (const float*)d_in[2];
    // d_in[3] = phi_f: dead for the 'enhanced' output
    const float* p1   = (const float*)d_in[4];
    const float* hr   = (const float*)d_in[5];
    const float* hi   = (const float*)d_in[6];
    float* out = (float*)d_out;

    const int B = in_sizes[0] / 256;  // N_MIC == 1
    pbfd_kernel<<<B, 64, 0, stream>>>(mic, lsb, phie, p1, hr, hi, out);
}

// Round 16
// 37.001 us; speedup vs baseline: 1.1297x; 1.0344x over previous
//
#include <hip/hip_runtime.h>
#include <math.h>

#define SF 0.99999f
#define PI2 6.283185307179586476925f
#define SWZ(c) ((c) ^ (((c) >> 4) & 15))
// compiler-only fence: orders same-wave LDS write/read phases.
#define LDSFENCE() asm volatile("" ::: "memory")

template<int SGN>
__device__ __forceinline__ void twmul(float& ur, float& ui, float c, float s) {
    const float ss = (SGN < 0) ? -s : s;
    const float r = ur * c - ui * ss;
    const float i = ui * c + ur * ss;
    ur = r; ui = i;
}

// 8-point DFT across registers. SGN=-1: forward; SGN=+1: inverse.
template<int SGN>
__device__ __forceinline__ void bfly8(float* ur, float* ui) {
    const float C2 = 0.70710678118654752440f;
    float ar[4], ai[4], br[4], bi[4];
#pragma unroll
    for (int m = 0; m < 4; ++m) {
        ar[m] = ur[m] + ur[m + 4]; ai[m] = ui[m] + ui[m + 4];
        br[m] = ur[m] - ur[m + 4]; bi[m] = ui[m] - ui[m + 4];
    }
    float b1r, b1i, b2r, b2i, b3r, b3i;
    if (SGN < 0) {
        b1r = C2 * (br[1] + bi[1]); b1i = C2 * (bi[1] - br[1]);
        b2r = bi[2];                b2i = -br[2];
        b3r = C2 * (bi[3] - br[3]); b3i = -C2 * (br[3] + bi[3]);
    } else {
        b1r = C2 * (br[1] - bi[1]); b1i = C2 * (bi[1] + br[1]);
        b2r = -bi[2];               b2i = br[2];
        b3r = -C2 * (br[3] + bi[3]); b3i = C2 * (br[3] - bi[3]);
    }
    const float e0r = ar[0] + ar[2], e0i = ai[0] + ai[2];
    const float e1r = ar[0] - ar[2], e1i = ai[0] - ai[2];
    const float o0r = ar[1] + ar[3], o0i = ai[1] + ai[3];
    const float o1r = ar[1] - ar[3], o1i = ai[1] - ai[3];
    ur[0] = e0r + o0r; ui[0] = e0i + o0i;
    ur[4] = e0r - o0r; ui[4] = e0i - o0i;
    if (SGN < 0) { ur[2] = e1r + o1i; ui[2] = e1i - o1r; ur[6] = e1r - o1i; ui[6] = e1i + o1r; }
    else         { ur[2] = e1r - o1i; ui[2] = e1i + o1r; ur[6] = e1r + o1i; ui[6] = e1i - o1r; }
    const float f0r = br[0] + b2r, f0i = bi[0] + b2i;
    const float f1r = br[0] - b2r, f1i = bi[0] - b2i;
    const float g0r = b1r + b3r, g0i = b1i + b3i;
    const float g1r = b1r - b3r, g1i = b1i - b3i;
    ur[1] = f0r + g0r; ui[1] = f0i + g0i;
    ur[5] = f0r - g0r; ui[5] = f0i - g0i;
    if (SGN < 0) { ur[3] = f1r + g1i; ui[3] = f1i - g1r; ur[7] = f1r - g1i; ui[7] = f1i + g1r; }
    else         { ur[3] = f1r - g1i; ui[3] = f1i + g1r; ur[7] = f1r + g1i; ui[7] = f1i - g1r; }
}

// Wave-local 512-pt complex FFT, Stockham radix-8, 3 stages, single LDS buffer.
// ra[8] = hoisted read indices SWZ(t+64m). Writes per-element inline SWZ.
// No barriers (single-wave workgroup; LDS ops retire in order per wave).
template<int SGN>
__device__ __forceinline__ void fft512w(float* ur, float* ui,
                                        float2* __restrict__ buf,
                                        const float2* __restrict__ tw2,
                                        const float2* __restrict__ tw3,
                                        const int* ra, int t) {
    bfly8<SGN>(ur, ui);
    LDSFENCE();
#pragma unroll
    for (int m = 0; m < 8; ++m) buf[SWZ(8 * t + m)] = make_float2(ur[m], ui[m]);
    LDSFENCE();
#pragma unroll
    for (int m = 0; m < 8; ++m) { const float2 v = buf[ra[m]]; ur[m] = v.x; ui[m] = v.y; }
    const int k2 = t & 7;
#pragma unroll
    for (int m = 1; m < 8; ++m) { const float2 w = tw2[m * 8 + k2]; twmul<SGN>(ur[m], ui[m], w.x, w.y); }
    bfly8<SGN>(ur, ui);
    const int jj = ((t >> 3) << 6) + k2;
    LDSFENCE();
#pragma unroll
    for (int m = 0; m < 8; ++m) buf[SWZ(jj + 8 * m)] = make_float2(ur[m], ui[m]);
    LDSFENCE();
#pragma unroll
    for (int m = 0; m < 8; ++m) { const float2 v = buf[ra[m]]; ur[m] = v.x; ui[m] = v.y; }
#pragma unroll
    for (int m = 1; m < 8; ++m) { const float2 w = tw3[m * 64 + t]; twmul<SGN>(ur[m], ui[m], w.x, w.y); }
    bfly8<SGN>(ur, ui);
    LDSFENCE();
}

// ONE WAVE PER BLOCK, TWO ELEMENTS PER WAVE (sequential): halves total wave
// count (4096 -> 2048) at identical total work. Discriminates the
// wave-throughput-bound hypothesis. No __syncthreads anywhere.
__global__ __launch_bounds__(64, 2) void pbfd_kernel(
    const float* __restrict__ g_mic,   // (B,256)
    const float* __restrict__ g_lsb,   // (B,1280)
    const float* __restrict__ g_phie,  // (B,257)
    const float* __restrict__ g_p1,    // (B,257,4)
    const float* __restrict__ g_hr,    // (B,257,4)
    const float* __restrict__ g_hi,    // (B,257,4)
    float* __restrict__ g_out,         // (B,256)
    int B)
{
    __shared__ float2 tw2[64];
    __shared__ float2 tw3[512];
    __shared__ float2 xch[512];

    const int t = threadIdx.x;         // 0..63
    float2* buf = &xch[0];
    const int ml = (64 - t) & 63;  // mirror lane: bin 512-k lives at (ml, 7-m) for t>=1

    // ---- per-block twiddle tables, built once, shared by both elements ----
    {
        float s3, c3;
        sincosf(PI2 * (float)t * (1.0f / 512.0f), &s3, &c3);
        float cr = 1.f, ci = 0.f;
#pragma unroll
        for (int m = 0; m < 8; ++m) {
            tw3[m * 64 + t] = make_float2(cr, ci);
            const float nr = cr * c3 - ci * s3;
            ci = ci * c3 + cr * s3;
            cr = nr;
        }
        float s2, c2;
        sincosf(PI2 * (float)((t >> 3) * (t & 7)) * (1.0f / 64.0f), &s2, &c2);
        tw2[t] = make_float2(c2, s2);
    }
    LDSFENCE();

    // ---- hoisted LDS read indices (element-independent) ----
    int ra[8];
#pragma unroll
    for (int m = 0; m < 8; ++m) ra[m] = SWZ(t + 64 * m);

#pragma unroll 1
    for (int ee = 0; ee < 2; ++ee) {
        const int elem = blockIdx.x * 2 + ee;
        if (elem >= B) break;

        float mv[4];
        {
            const float* mp = g_mic + (size_t)elem * 256;
#pragma unroll
            for (int q = 0; q < 4; ++q) mv[q] = mp[t + 64 * q];
        }

        // ---- X: 4 real frame-FFTs as 2 paired complex FFTs; low bins + lane0 Nyquist ----
        float xr[4][4], xi[4][4], xn[4];
        {
            const float* lb = g_lsb + (size_t)elem * 1280;
#pragma unroll
            for (int pr = 0; pr < 2; ++pr) {
                float ur[8], ui[8];
#pragma unroll
                for (int m = 0; m < 8; ++m) {
                    ur[m] = lb[(2 * pr) * 256 + t + 64 * m];
                    ui[m] = lb[(2 * pr + 1) * 256 + t + 64 * m];
                }
                fft512w<-1>(ur, ui, buf, tw2, tw3, ra, t);
#pragma unroll
                for (int m = 0; m < 4; ++m) {
                    float zmr = __shfl(ur[7 - m], ml);
                    float zmi = __shfl(ui[7 - m], ml);
                    if (t == 0) {  // lane0: mirror of bin 64m is slot 8-m (self for m=0)
                        zmr = (m == 0) ? ur[0] : ur[8 - m];
                        zmi = (m == 0) ? ui[0] : ui[8 - m];
                    }
                    xr[2 * pr][m]     = 0.5f * (ur[m] + zmr);
                    xi[2 * pr][m]     = 0.5f * (ui[m] - zmi);
                    xr[2 * pr + 1][m] = 0.5f * (ui[m] + zmi);
                    xi[2 * pr + 1][m] = -0.5f * (ur[m] - zmr);
                }
                if (t == 0) { xn[2 * pr] = ur[4]; xn[2 * pr + 1] = ui[4]; }  // X[256] re/im
            }
        }

        // Hermitian IFFT: o4[q] = Re(ifft)[256+t+64q]/512.
        auto herm_ifft = [&](const float cr[4], const float ci[4], float cn, float o4[4]) {
            float ur[8], ui[8];
#pragma unroll
            for (int m = 0; m < 4; ++m) { ur[m] = cr[m]; ui[m] = ci[m]; }
#pragma unroll
            for (int m = 4; m < 8; ++m) {  // high slot = conj(mirror-lane low slot 7-m)
                ur[m] = __shfl(cr[7 - m], ml);
                ui[m] = -__shfl(ci[7 - m], ml);
            }
            if (t == 0) {
                ur[5] = cr[3]; ui[5] = -ci[3];
                ur[6] = cr[2]; ui[6] = -ci[2];
                ur[7] = cr[1]; ui[7] = -ci[1];
                ur[4] = cn; ui[4] = 0.f;  // Nyquist: real
            }
            fft512w<1>(ur, ui, buf, tw2, tw3, ra, t);
#pragma unroll
            for (int q = 0; q < 4; ++q) o4[q] = ur[4 + q] * (1.0f / 512.0f);
        };

        // ---- est (H prior): C = sum_j X*H; d = mic - est.  H dies after this block. ----
        float d4[4];
        float pn[4], en = 0.f, pen = 0.f;  // lane0 side channel
        {
            float cr[4], ci[4], cn = 0.f;
            const float4* hr4 = (const float4*)g_hr + (size_t)elem * 257;
            const float4* hi4 = (const float4*)g_hi + (size_t)elem * 257;
#pragma unroll
            for (int m = 0; m < 4; ++m) {
                const float4 a = hr4[t + 64 * m];
                const float4 b = hi4[t + 64 * m];
                cr[m] = xr[0][m] * a.x - xi[0][m] * b.x + xr[1][m] * a.y - xi[1][m] * b.y
                      + xr[2][m] * a.z - xi[2][m] * b.z + xr[3][m] * a.w - xi[3][m] * b.w;
                ci[m] = xr[0][m] * b.x + xi[0][m] * a.x + xr[1][m] * b.y + xi[1][m] * a.y
                      + xr[2][m] * b.z + xi[2][m] * a.z + xr[3][m] * b.w + xi[3][m] * a.w;
            }
            if (t == 0) {
                const float4 a = hr4[256];
                const float4 p = ((const float4*)g_p1)[(size_t)elem * 257 + 256];
                cn = xn[0] * a.x + xn[1] * a.y + xn[2] * a.z + xn[3] * a.w;
                pn[0] = p.x; pn[1] = p.y; pn[2] = p.z; pn[3] = p.w;
            }
            float o4[4];
            herm_ifft(cr, ci, cn, o4);
#pragma unroll
            for (int q = 0; q < 4; ++q) d4[q] = mv[q] - o4[q];
        }

        // ---- E = FFT([zeros(256); d]) ----
        float er[4], ei[4];
        {
            float ur[8], ui[8];
#pragma unroll
            for (int m = 0; m < 4; ++m) { ur[m] = 0.f; ui[m] = 0.f; }
#pragma unroll
            for (int q = 0; q < 4; ++q) { ur[4 + q] = d4[q]; ui[4 + q] = 0.f; }
            fft512w<-1>(ur, ui, buf, tw2, tw3, ra, t);
#pragma unroll
            for (int m = 0; m < 4; ++m) { er[m] = ur[m]; ei[m] = ui[m]; }
            if (t == 0) en = ur[4];
        }

        // ---- phi_e ----
        float pe[4];
        {
            const float* php = g_phie + (size_t)elem * 257;
#pragma unroll
            for (int m = 0; m < 4; ++m)
                pe[m] = 0.7f * php[t + 64 * m] + 0.3f * (er[m] * er[m] + ei[m] * ei[m]);
            if (t == 0) pen = 0.7f * php[256] + 0.3f * en * en;
        }

        // ---- gradient: pairs (0,1),(2,3): IFFT(KE0+i*KE1) -> mask -> FFT ->
        //      unpack fd_dH, accumulate D = sum_j X_j * fd_dH_j ----
        float Dr[4] = {0, 0, 0, 0}, Di[4] = {0, 0, 0, 0};
        float dn = 0.f;  // lane0: D at Nyquist
        {
            const float4* p14 = (const float4*)g_p1 + (size_t)elem * 257;
#pragma unroll
            for (int pr = 0; pr < 2; ++pr) {
                const int j0 = 2 * pr, j1 = 2 * pr + 1;
                float ur[8], ui[8], gr[4], gi[4];
#pragma unroll
                for (int m = 0; m < 4; ++m) {
                    // KE_j = P1_j * conj(X_j) / R_j * E
                    const float4 p = p14[t + 64 * m];
                    const float pa = pr ? p.z : p.x;
                    const float pb = pr ? p.w : p.y;
                    const float xxa = xr[j0][m] * xr[j0][m] + xi[j0][m] * xi[j0][m];
                    const float Ra = xxa * pa + 2.f * pe[m] + 1e-10f;
                    const float ia = 1.f / Ra;
                    const float kra = pa * xr[j0][m] * ia, kia = -pa * xi[j0][m] * ia;
                    const float a_r = kra * er[m] - kia * ei[m];
                    const float a_i = kra * ei[m] + kia * er[m];
                    const float xxb = xr[j1][m] * xr[j1][m] + xi[j1][m] * xi[j1][m];
                    const float Rb = xxb * pb + 2.f * pe[m] + 1e-10f;
                    const float ib = 1.f / Rb;
                    const float krb = pb * xr[j1][m] * ib, kib = -pb * xi[j1][m] * ib;
                    const float b_r = krb * er[m] - kib * ei[m];
                    const float b_i = krb * ei[m] + kib * er[m];
                    ur[m] = a_r - b_i;  ui[m] = a_i + b_r;   // KE0 + i*KE1
                    gr[m] = a_r + b_i;  gi[m] = b_r - a_i;   // conj-pack for mirror lanes
                }
#pragma unroll
                for (int m = 4; m < 8; ++m) {
                    ur[m] = __shfl(gr[7 - m], ml);
                    ui[m] = __shfl(gi[7 - m], ml);
                }
                if (t == 0) {
                    ur[5] = gr[3]; ui[5] = gi[3];
                    ur[6] = gr[2]; ui[6] = gi[2];
                    ur[7] = gr[1]; ui[7] = gi[1];
                    const float Rn0 = xn[j0] * xn[j0] * pn[j0] + 2.f * pen + 1e-10f;
                    const float Rn1 = xn[j1] * xn[j1] * pn[j1] + 2.f * pen + 1e-10f;
                    ur[4] = pn[j0] * xn[j0] / Rn0 * en;   // KE0[256] (real)
                    ui[4] = pn[j1] * xn[j1] / Rn1 * en;   // KE1[256] (real)
                }
                fft512w<1>(ur, ui, buf, tw2, tw3, ra, t);  // -> 512*(dH0 + i*dH1)
                // mask n<256 (slots m<4), scale 1/512, FFT the still-packed pair
#pragma unroll
                for (int m = 0; m < 4; ++m) { ur[m] *= (1.0f / 512.0f); ui[m] *= (1.0f / 512.0f); }
#pragma unroll
                for (int m = 4; m < 8; ++m) { ur[m] = 0.f; ui[m] = 0.f; }
                fft512w<-1>(ur, ui, buf, tw2, tw3, ra, t);  // Z = fd_dH0 + i*fd_dH1
                // unpack at low slots; accumulate D += X_j0*fd0 + X_j1*fd1
#pragma unroll
                for (int m = 0; m < 4; ++m) {
                    float zmr = __shfl(ur[7 - m], ml);
                    float zmi = __shfl(ui[7 - m], ml);
                    if (t == 0) {
                        zmr = (m == 0) ? ur[0] : ur[8 - m];
                        zmi = (m == 0) ? ui[0] : ui[8 - m];
                    }
                    const float f0r = 0.5f * (ur[m] + zmr), f0i = 0.5f * (ui[m] - zmi);
                    const float f1r = 0.5f * (ui[m] + zmi), f1i = -0.5f * (ur[m] - zmr);
                    Dr[m] += xr[j0][m] * f0r - xi[j0][m] * f0i + xr[j1][m] * f1r - xi[j1][m] * f1i;
                    Di[m] += xr[j0][m] * f0i + xi[j0][m] * f0r + xr[j1][m] * f1i + xi[j1][m] * f1r;
                }
                if (t == 0) dn += xn[j0] * ur[4] + xn[j1] * ui[4];  // fd_dH nyq
            }
        }

        // ---- enhanced = mic - SF*(est + irfft(D)[256:]) ;  est = mic - d ----
        {
            float o4[4];
            herm_ifft(Dr, Di, dn, o4);
            float* op = g_out + (size_t)elem * 256;
#pragma unroll
            for (int q = 0; q < 4; ++q)
                op[t + 64 * q] = mv[q] - SF * ((mv[q] - d4[q]) + o4[q]);
        }
    }
}

extern "C" void kernel_launch(void* const* d_in, const int* in_sizes, int n_in,
                              void* d_out, int out_size, void* d_ws, size_t ws_size,
                              hipStream_t stream) {
    const float* mic  = (const float*)d_in[0];
    const float* lsb  = (const float*)d_in[1];
    const float* phie = (const float*)d_in[2];
    // d_in[3] = phi_f: dead for the 'enhanced' output
    const float* p1   = (const float*)d_in[4];
    const float* hr   = (const float*)d_in[5];
    const float* hi   = (const float*)d_in[6];
    float* out = (float*)d_out;

    const int B = in_sizes[0] / 256;  // N_MIC == 1
    const int blocks = (B + 1) / 2;   // 2 elements per single-wave block
    pbfd_kernel<<<blocks, 64, 0, stream>>>(mic, lsb, phie, p1, hr, hi, out, B);
}